// Round 6
// baseline (1203.168 us; speedup 1.0000x reference)
//
#include <hip/hip_runtime.h>
#include <hip/hip_bf16.h>

#define N_TOK   8192
#define DM      1024     // d_model
#define DH      16384    // d_hidden
#define KTOP    32
#define NCAND   512      // candidate slots per row (64 col-blocks x 8)
#define SLOTS   8        // slots per (row, 256-col block)
#define CAND_T  2.2f     // fixed threshold (validated end-to-end in round 3)
#define DZ      0.08f    // zone half-width >= 2*delta (delta <= 0.035 incl bf16 quant)
#define NT      16       // K-tiles of 64

typedef unsigned int uint;
typedef __attribute__((ext_vector_type(8))) short bf16x8;
typedef __attribute__((ext_vector_type(4))) float f32x4;

__device__ inline ushort f2bf(float f) {
    uint u = __float_as_uint(f);
    uint r = (u + 0x7FFFu + ((u >> 16) & 1u)) >> 16;
    return (ushort)r;
}
__device__ inline float bf2f(ushort u) {
    return __uint_as_float(((uint)u) << 16);
}

__device__ inline void load_lds16(const void* g, void* l) {
    __builtin_amdgcn_global_load_lds(
        (const __attribute__((address_space(1))) void*)g,
        (__attribute__((address_space(3))) void*)l, 16, 0, 0);
}

// ---------------------------------------------------------------------------
// Convert x -> bf16(x - b_pre)   [N_TOK, DM]
// ---------------------------------------------------------------------------
__global__ __launch_bounds__(256) void conv_x(
    const float* __restrict__ x, const float* __restrict__ b_pre,
    ushort* __restrict__ A)
{
    int i = (blockIdx.x * 256 + threadIdx.x) * 4;
    float4 v = *(const float4*)&x[i];
    float4 b = *(const float4*)&b_pre[i & (DM - 1)];
    ushort4 o;
    o.x = f2bf(v.x - b.x); o.y = f2bf(v.y - b.y);
    o.z = f2bf(v.z - b.z); o.w = f2bf(v.w - b.w);
    *(ushort4*)&A[i] = o;
}

// Convert W_enc -> bf16   [DH, DM]
__global__ __launch_bounds__(256) void conv_w(
    const float* __restrict__ W, ushort* __restrict__ B)
{
    int i = (blockIdx.x * 256 + threadIdx.x) * 4;
    float4 v = *(const float4*)&W[i];
    ushort4 o;
    o.x = f2bf(v.x); o.y = f2bf(v.y); o.z = f2bf(v.z); o.w = f2bf(v.w);
    *(ushort4*)&B[i] = o;
}

// ---------------------------------------------------------------------------
// 256x256 8-phase bf16 MFMA GEMM + fused candidate extraction.
// pre[n][h] = A[n][:] . B[h][:] + b_act[h]; candidates (o > CAND_T) go to
// fixed per-(row, col-block) slots via LDS aggregation (no global atomics).
// Last K-tile peeled (no staging; vmcnt(4)/vmcnt(0)) to avoid dup loads.
// ---------------------------------------------------------------------------
#define LDS_A(par, ks)  ((par) * 65536 + (ks) * 16384)
#define LDS_B(par, ks)  ((par) * 65536 + 32768 + (ks) * 16384)

__global__ __launch_bounds__(512, 2) void gemm8ph(
    const ushort* __restrict__ A, const ushort* __restrict__ B,
    const float* __restrict__ b_act, float* __restrict__ pre,
    uint* __restrict__ cand, uint* __restrict__ flags)
{
    __shared__ __align__(16) char smem[131072];

    const int tid  = threadIdx.x;
    const int wid  = tid >> 6;
    const int lane = tid & 63;
    const int wm   = wid >> 2;        // 0..1
    const int wn   = wid & 3;         // 0..3

    const int swz  = (blockIdx.x & 7) * 256 + (blockIdx.x >> 3);
    const int row0 = (swz & 31) * 256;
    const int col0 = (swz >> 5) * 256;

    f32x4 acc[8][4] = {};

    auto stage = [&](const ushort* __restrict__ g, int grow0, int gk0,
                     int region) {
        #pragma unroll
        for (int i = 0; i < 2; ++i) {
            int c    = i * 512 + wid * 64 + lane;
            int row  = c >> 2;
            int slot = (c & 3) ^ ((row >> 1) & 3);
            load_lds16(g + (size_t)(grow0 + row) * DM + gk0 + slot * 8,
                       smem + region + (i * 512 + wid * 64) * 16);
        }
    };
    auto ld_frag = [&](int region, int row) -> bf16x8 {
        int slot = (lane >> 4) ^ ((row >> 1) & 3);
        return *(const bf16x8*)(smem + region + row * 64 + slot * 16);
    };

    const int ar = wm * 128 + (lane & 15);
    const int br = wn * 64 + (lane & 15);

    // prologue: stage tile 0
    stage(A, row0, 0,  LDS_A(0, 0));
    stage(B, col0, 0,  LDS_B(0, 0));
    stage(A, row0, 32, LDS_A(0, 1));
    stage(B, col0, 32, LDS_B(0, 1));

    for (int t = 0; t < NT - 1; ++t) {
        const int par  = t & 1;
        const int npar = par ^ 1;
        const int k0n  = (t + 1) * 64;

        // ---- phase 0
        stage(A, row0, k0n, LDS_A(npar, 0));
        asm volatile("s_waitcnt vmcnt(6)" ::: "memory");
        __builtin_amdgcn_s_barrier();
        asm volatile("" ::: "memory");

        bf16x8 af[8];
        #pragma unroll
        for (int mf = 0; mf < 8; ++mf)
            af[mf] = ld_frag(LDS_A(par, 0), ar + mf * 16);
        {
            bf16x8 b0 = ld_frag(LDS_B(par, 0), br);
            bf16x8 b1 = ld_frag(LDS_B(par, 0), br + 16);
            __builtin_amdgcn_s_setprio(1);
            #pragma unroll
            for (int mf = 0; mf < 8; ++mf) {
                acc[mf][0] = __builtin_amdgcn_mfma_f32_16x16x32_bf16(af[mf], b0, acc[mf][0], 0, 0, 0);
                acc[mf][1] = __builtin_amdgcn_mfma_f32_16x16x32_bf16(af[mf], b1, acc[mf][1], 0, 0, 0);
            }
            __builtin_amdgcn_s_setprio(0);
        }
        // ---- phase 1
        stage(B, col0, k0n, LDS_B(npar, 0));
        {
            bf16x8 b2 = ld_frag(LDS_B(par, 0), br + 32);
            bf16x8 b3 = ld_frag(LDS_B(par, 0), br + 48);
            __builtin_amdgcn_s_setprio(1);
            #pragma unroll
            for (int mf = 0; mf < 8; ++mf) {
                acc[mf][2] = __builtin_amdgcn_mfma_f32_16x16x32_bf16(af[mf], b2, acc[mf][2], 0, 0, 0);
                acc[mf][3] = __builtin_amdgcn_mfma_f32_16x16x32_bf16(af[mf], b3, acc[mf][3], 0, 0, 0);
            }
            __builtin_amdgcn_s_setprio(0);
        }
        // ---- phase 2
        stage(A, row0, k0n + 32, LDS_A(npar, 1));
        asm volatile("s_waitcnt vmcnt(6)" ::: "memory");
        __builtin_amdgcn_s_barrier();
        asm volatile("" ::: "memory");

        #pragma unroll
        for (int mf = 0; mf < 8; ++mf)
            af[mf] = ld_frag(LDS_A(par, 1), ar + mf * 16);
        {
            bf16x8 b0 = ld_frag(LDS_B(par, 1), br);
            bf16x8 b1 = ld_frag(LDS_B(par, 1), br + 16);
            __builtin_amdgcn_s_setprio(1);
            #pragma unroll
            for (int mf = 0; mf < 8; ++mf) {
                acc[mf][0] = __builtin_amdgcn_mfma_f32_16x16x32_bf16(af[mf], b0, acc[mf][0], 0, 0, 0);
                acc[mf][1] = __builtin_amdgcn_mfma_f32_16x16x32_bf16(af[mf], b1, acc[mf][1], 0, 0, 0);
            }
            __builtin_amdgcn_s_setprio(0);
        }
        // ---- phase 3
        stage(B, col0, k0n + 32, LDS_B(npar, 1));
        {
            bf16x8 b2 = ld_frag(LDS_B(par, 1), br + 32);
            bf16x8 b3 = ld_frag(LDS_B(par, 1), br + 48);
            __builtin_amdgcn_s_setprio(1);
            #pragma unroll
            for (int mf = 0; mf < 8; ++mf) {
                acc[mf][2] = __builtin_amdgcn_mfma_f32_16x16x32_bf16(af[mf], b2, acc[mf][2], 0, 0, 0);
                acc[mf][3] = __builtin_amdgcn_mfma_f32_16x16x32_bf16(af[mf], b3, acc[mf][3], 0, 0, 0);
            }
            __builtin_amdgcn_s_setprio(0);
        }
    }

    // ---- peeled last tile (par = 1, nothing staged; counted waits adjusted)
    {
        const int par = (NT - 1) & 1;
        asm volatile("s_waitcnt vmcnt(4)" ::: "memory");   // A0,B0 of last tile landed
        __builtin_amdgcn_s_barrier();
        asm volatile("" ::: "memory");

        bf16x8 af[8];
        #pragma unroll
        for (int mf = 0; mf < 8; ++mf)
            af[mf] = ld_frag(LDS_A(par, 0), ar + mf * 16);
        {
            bf16x8 b0 = ld_frag(LDS_B(par, 0), br);
            bf16x8 b1 = ld_frag(LDS_B(par, 0), br + 16);
            bf16x8 b2 = ld_frag(LDS_B(par, 0), br + 32);
            bf16x8 b3 = ld_frag(LDS_B(par, 0), br + 48);
            __builtin_amdgcn_s_setprio(1);
            #pragma unroll
            for (int mf = 0; mf < 8; ++mf) {
                acc[mf][0] = __builtin_amdgcn_mfma_f32_16x16x32_bf16(af[mf], b0, acc[mf][0], 0, 0, 0);
                acc[mf][1] = __builtin_amdgcn_mfma_f32_16x16x32_bf16(af[mf], b1, acc[mf][1], 0, 0, 0);
                acc[mf][2] = __builtin_amdgcn_mfma_f32_16x16x32_bf16(af[mf], b2, acc[mf][2], 0, 0, 0);
                acc[mf][3] = __builtin_amdgcn_mfma_f32_16x16x32_bf16(af[mf], b3, acc[mf][3], 0, 0, 0);
            }
            __builtin_amdgcn_s_setprio(0);
        }
        asm volatile("s_waitcnt vmcnt(0)" ::: "memory");   // A1,B1 landed
        __builtin_amdgcn_s_barrier();
        asm volatile("" ::: "memory");

        #pragma unroll
        for (int mf = 0; mf < 8; ++mf)
            af[mf] = ld_frag(LDS_A(par, 1), ar + mf * 16);
        {
            bf16x8 b0 = ld_frag(LDS_B(par, 1), br);
            bf16x8 b1 = ld_frag(LDS_B(par, 1), br + 16);
            bf16x8 b2 = ld_frag(LDS_B(par, 1), br + 32);
            bf16x8 b3 = ld_frag(LDS_B(par, 1), br + 48);
            __builtin_amdgcn_s_setprio(1);
            #pragma unroll
            for (int mf = 0; mf < 8; ++mf) {
                acc[mf][0] = __builtin_amdgcn_mfma_f32_16x16x32_bf16(af[mf], b0, acc[mf][0], 0, 0, 0);
                acc[mf][1] = __builtin_amdgcn_mfma_f32_16x16x32_bf16(af[mf], b1, acc[mf][1], 0, 0, 0);
                acc[mf][2] = __builtin_amdgcn_mfma_f32_16x16x32_bf16(af[mf], b2, acc[mf][2], 0, 0, 0);
                acc[mf][3] = __builtin_amdgcn_mfma_f32_16x16x32_bf16(af[mf], b3, acc[mf][3], 0, 0, 0);
            }
            __builtin_amdgcn_s_setprio(0);
        }
    }

    // ---- epilogue: reuse LDS for per-row candidate aggregation
    __syncthreads();                       // all waves done with LDS tiles
    uint* cnt = (uint*)smem;               // [256]
    uint* buf = (uint*)(smem + 1024);      // [256][SLOTS]
    if (tid < 256) cnt[tid] = 0;
    __syncthreads();

    float bav[4];
    #pragma unroll
    for (int nf = 0; nf < 4; ++nf)
        bav[nf] = b_act[col0 + wn * 64 + nf * 16 + (lane & 15)];

    #pragma unroll
    for (int mf = 0; mf < 8; ++mf) {
        const int lrow = wm * 128 + mf * 16 + (lane >> 4) * 4;
        const int gcol = col0 + wn * 64 + (lane & 15);
        #pragma unroll
        for (int r = 0; r < 4; ++r) {
            #pragma unroll
            for (int nf = 0; nf < 4; ++nf) {
                float o = acc[mf][nf][r] + bav[nf];
                pre[(size_t)(row0 + lrow + r) * DH + gcol + nf * 16] = o;
                if (o > CAND_T) {
                    uint pos = atomicAdd(&cnt[lrow + r], 1u);
                    if (pos < SLOTS)
                        buf[(lrow + r) * SLOTS + pos] =
                            ((uint)f2bf(o) << 16) | (uint)(16383 - (gcol + nf * 16));
                }
            }
        }
    }
    __syncthreads();
    if (tid < 256) {
        uint c = cnt[tid];
        uint m = c < SLOTS ? c : SLOTS;
        const size_t base = (size_t)(row0 + tid) * NCAND + (col0 >> 8) * SLOTS;
        for (uint k = 0; k < m; ++k)
            cand[base + k] = buf[tid * SLOTS + k];
        if (c > SLOTS) flags[row0 + tid] = 1u;
    }
}

// ---------------------------------------------------------------------------
// Fused top-32: read candidate slots (4 KB/row instead of 64 KB pre row),
// compact, fallback to full-row bisection if overflow/degenerate, then the
// proven rank/zone/exact-repair logic. Also zeroes the sparse row.
// ---------------------------------------------------------------------------
__global__ __launch_bounds__(512) void topk_fused(
    const float* __restrict__ x, const float* __restrict__ b_pre,
    const float* __restrict__ W, const float* __restrict__ b_act,
    const uint* __restrict__ cand, const uint* __restrict__ flags,
    const float* __restrict__ pre,
    float* __restrict__ sparse, float* __restrict__ vals, int* __restrict__ inds)
{
    const int row = blockIdx.x;
    const int tid = threadIdx.x;
    const int wid = tid >> 6, lane = tid & 63;

    // zero sparse row (4096 float4 / 512 threads)
    float4 z4 = {0.f, 0.f, 0.f, 0.f};
    float4* srow = (float4*)(sparse + (size_t)row * DH);
    #pragma unroll
    for (int i = 0; i < 8; ++i) srow[tid + i * 512] = z4;

    __shared__ float xs[DM];
    for (int i = tid; i < DM; i += 512)
        xs[i] = x[(size_t)row * DM + i] - b_pre[i];

    __shared__ float sv[NCAND];
    __shared__ float sex[NCAND];
    __shared__ int   si[NCAND];
    __shared__ int   zlist[NCAND];
    __shared__ unsigned char zf[NCAND];
    __shared__ float sa32;
    __shared__ int   scin, zn, nl;

    sv[tid] = -1e30f; si[tid] = -1;
    if (tid == 0) { scin = 0; zn = 0; nl = 0; sa32 = -1e30f; }
    if (tid < KTOP) {
        vals[(size_t)row * KTOP + tid] = 0.f;
        inds[(size_t)row * KTOP + tid] = -1;
    }
    __syncthreads();

    // compact candidate slots
    uint pk = cand[(size_t)row * NCAND + tid];
    if (pk) {
        int p = atomicAdd(&nl, 1);
        sv[p] = bf2f((ushort)(pk >> 16));
        si[p] = 16383 - (int)(pk & 0x3FFFu);
    }
    __syncthreads();
    int n = nl;

    // fallback: overflowed / degenerate rows re-scan their pre row (rare)
    const bool fb = (flags[row] != 0u) || n < 96 || n > 500;
    if (fb) {
        __syncthreads();
        sv[tid] = -1e30f; si[tid] = -1;
        if (tid == 0) nl = 0;
        const float* __restrict__ p = pre + (size_t)row * DH;
        float v[32];
        #pragma unroll
        for (int j = 0; j < 32; ++j) v[j] = p[j * 512 + tid];

        __shared__ int scount;
        float lo = -30.f, hi = 30.f, t = 0.f;
        for (int it = 0; it < 20; ++it) {
            t = 0.5f * (lo + hi);
            int c = 0;
            #pragma unroll
            for (int j = 0; j < 32; ++j) c += (v[j] > t);
            #pragma unroll
            for (int off = 32; off; off >>= 1) c += __shfl_down(c, off);
            if (tid == 0) scount = 0;
            __syncthreads();
            if ((tid & 63) == 0) atomicAdd(&scount, c);
            __syncthreads();
            int total = scount;
            __syncthreads();
            if (total >= 96 && total <= 450) break;
            if (total < 96) hi = t; else lo = t;
        }
        #pragma unroll
        for (int j = 0; j < 32; ++j) {
            if (v[j] > t) {
                int p2 = atomicAdd(&nl, 1);
                if (p2 < NCAND) { sv[p2] = v[j]; si[p2] = j * 512 + tid; }
            }
        }
        __syncthreads();
        n = min(nl, NCAND);
    }

    const float v  = sv[tid];
    const int   id = si[tid];
    sex[tid] = v;
    __syncthreads();

    // rank by count (val desc, idx asc)
    int rank = 0;
    for (int j = 0; j < NCAND; ++j) {
        float ov = sv[j];
        rank += (ov > v) || (ov == v && si[j] < id);
    }
    if (rank == 31) sa32 = v;
    __syncthreads();

    const float a32 = sa32;
    const bool cin  = v > a32 + DZ;
    const bool zone = !cin && (v >= a32 - DZ) && (id >= 0);

    unsigned long long bal = __ballot(cin);
    if (lane == 0) atomicAdd(&scin, (int)__popcll(bal));
    if (zone) { int p = atomicAdd(&zn, 1); zlist[p] = tid; }
    zf[tid] = zone ? 1 : 0;
    __syncthreads();

    const int cin_total = scin;
    const int znum = zn;

    // exact f32 recompute of zone members, one per wave (W rows L3-resident)
    for (int m = wid; m < znum; m += 8) {
        int t = zlist[m];
        int h = si[t];
        const float* wrow = W + (size_t)h * DM;
        float s = 0.f;
        #pragma unroll
        for (int c = 0; c < 16; ++c)
            s = fmaf(xs[lane + c * 64], wrow[lane + c * 64], s);
        #pragma unroll
        for (int off = 32; off; off >>= 1) s += __shfl_down(s, off);
        if (lane == 0) sex[t] = s + b_act[h];
    }
    __syncthreads();

    int slot = -1;
    float outv = 0.f;
    if (cin) { slot = rank; outv = v; }
    else if (zone) {
        float ev = sex[tid];
        int zrank = 0;
        for (int j = 0; j < NCAND; ++j) {
            if (zf[j]) {
                float ov = sex[j];
                zrank += (ov > ev) || (ov == ev && si[j] < id);
            }
        }
        if (zrank < KTOP - cin_total) { slot = cin_total + zrank; outv = ev; }
    }
    if (slot >= 0 && slot < KTOP) {
        float r = fmaxf(outv, 0.f);
        vals[(size_t)row * KTOP + slot] = r;
        inds[(size_t)row * KTOP + slot] = id;
        sparse[(size_t)row * DH + id] = r;
    }
}

// ---------------------------------------------------------------------------
// Transpose W_dec [DM, DH] f32 -> W_dec^T [DH, DM] bf16
// ---------------------------------------------------------------------------
__global__ __launch_bounds__(256) void transpose_dec(
    const float* __restrict__ W, ushort* __restrict__ WT)
{
    __shared__ float t[32][33];
    const int tx = threadIdx.x;
    const int ty = threadIdx.y;
    const int h0 = blockIdx.x * 32;
    const int d0 = blockIdx.y * 32;
    #pragma unroll
    for (int r = 0; r < 4; ++r)
        t[ty + r * 8][tx] = W[(size_t)(d0 + ty + r * 8) * DH + h0 + tx];
    __syncthreads();
    #pragma unroll
    for (int r = 0; r < 4; ++r)
        WT[(size_t)(h0 + ty + r * 8) * DM + d0 + tx] = f2bf(t[tx][ty + r * 8]);
}

// ---------------------------------------------------------------------------
// Decode: recon[n][d] = sum_j vals[n][j] * WdecT[inds[n][j]][d] + b_pre[d]
// ---------------------------------------------------------------------------
__global__ __launch_bounds__(256) void recon_kernel(
    const float* __restrict__ vals, const int* __restrict__ inds,
    const ushort* __restrict__ wdecT, const float* __restrict__ b_pre,
    float* __restrict__ recon)
{
    const int row = blockIdx.x;
    const int tid = threadIdx.x;
    __shared__ float lval[KTOP];
    __shared__ int   lind[KTOP];
    if (tid < KTOP) {
        lval[tid] = vals[(size_t)row * KTOP + tid];
        lind[tid] = inds[(size_t)row * KTOP + tid];
    }
    __syncthreads();

    const int d = tid * 4;
    float4 a = *(const float4*)&b_pre[d];
    #pragma unroll 8
    for (int j = 0; j < KTOP; ++j) {
        float vj = lval[j];
        int h = lind[j];
        if (vj != 0.f && h >= 0) {
            ushort4 w = *(const ushort4*)&wdecT[(size_t)h * DM + d];
            a.x = fmaf(vj, bf2f(w.x), a.x);
            a.y = fmaf(vj, bf2f(w.y), a.y);
            a.z = fmaf(vj, bf2f(w.z), a.z);
            a.w = fmaf(vj, bf2f(w.w), a.w);
        }
    }
    *(float4*)&recon[(size_t)row * DM + d] = a;
}

// ---------------------------------------------------------------------------
extern "C" void kernel_launch(void* const* d_in, const int* in_sizes, int n_in,
                              void* d_out, int out_size, void* d_ws, size_t ws_size,
                              hipStream_t stream)
{
    const float* x     = (const float*)d_in[0];
    const float* W_enc = (const float*)d_in[1];
    const float* W_dec = (const float*)d_in[2];
    const float* b_pre = (const float*)d_in[3];
    const float* b_act = (const float*)d_in[4];

    float* recon  = (float*)d_out;                       // [N, DM]
    float* sparse = recon + (size_t)N_TOK * DM;          // [N, DH]
    float* pre    = sparse + (size_t)N_TOK * DH;         // [N, DH]

    // bf16 staging of A/B inside the sparse output region (zeroed later by
    // topk_fused, which runs after gemm has consumed them)
    ushort* Abf = (ushort*)sparse;                       // 16.8 MB
    ushort* Bbf = Abf + (size_t)N_TOK * DM;              // 33.5 MB

    // workspace (~52.4 MB, proven footprint)
    uint*   cand  = (uint*)d_ws;                                  // 16.78 MB
    uint*   flags = cand + (size_t)N_TOK * NCAND;                 // 32 KB
    float*  vals  = (float*)(flags + N_TOK);                      // 1.05 MB
    int*    inds  = (int*)(vals + (size_t)N_TOK * KTOP);          // 1.05 MB
    ushort* wdecT = (ushort*)(inds + (size_t)N_TOK * KTOP);       // 33.5 MB

    // zero candidate slots + overflow flags (contiguous)
    hipMemsetAsync(cand, 0, ((size_t)N_TOK * NCAND + N_TOK) * sizeof(uint), stream);

    conv_x<<<N_TOK * DM / 1024, 256, 0, stream>>>(x, b_pre, Abf);
    conv_w<<<DH * DM / 1024, 256, 0, stream>>>(W_enc, Bbf);

    gemm8ph<<<(N_TOK / 256) * (DH / 256), 512, 0, stream>>>(
        Abf, Bbf, b_act, pre, cand, flags);

    transpose_dec<<<dim3(DH / 32, DM / 32), dim3(32, 8), 0, stream>>>(W_dec, wdecT);

    topk_fused<<<N_TOK, 512, 0, stream>>>(x, b_pre, W_enc, b_act,
                                          cand, flags, pre, sparse, vals, inds);

    recon_kernel<<<N_TOK, 256, 0, stream>>>(vals, inds, wdecT, b_pre, recon);
}

// Round 7
// 799.627 us; speedup vs baseline: 1.5047x; 1.5047x over previous
//
#include <hip/hip_runtime.h>
#include <hip/hip_bf16.h>

#define N_TOK   8192
#define DM      1024     // d_model
#define DH      16384    // d_hidden
#define KTOP    32
#define NCAND   512      // candidate capacity per row (atomic-range packed)
#define CSLOT   24       // LDS slots per (row, 256-col block); P(>24) ~ 1e-10
#define CAND_T  2.2f     // fixed threshold (validated end-to-end rounds 3/6)
#define DZ      0.08f    // zone half-width >= gemm err (0.031) + bf16 quant (0.016)
#define NT      16       // K-tiles of 64

typedef unsigned int uint;
typedef __attribute__((ext_vector_type(8))) short bf16x8;
typedef __attribute__((ext_vector_type(4))) float f32x4;

__device__ inline ushort f2bf(float f) {
    uint u = __float_as_uint(f);
    uint r = (u + 0x7FFFu + ((u >> 16) & 1u)) >> 16;
    return (ushort)r;
}
__device__ inline float bf2f(ushort u) {
    return __uint_as_float(((uint)u) << 16);
}

__device__ inline void load_lds16(const void* g, void* l) {
    __builtin_amdgcn_global_load_lds(
        (const __attribute__((address_space(1))) void*)g,
        (__attribute__((address_space(3))) void*)l, 16, 0, 0);
}

// ---------------------------------------------------------------------------
// Convert x -> bf16(x - b_pre)   [N_TOK, DM]
// ---------------------------------------------------------------------------
__global__ __launch_bounds__(256) void conv_x(
    const float* __restrict__ x, const float* __restrict__ b_pre,
    ushort* __restrict__ A)
{
    int i = (blockIdx.x * 256 + threadIdx.x) * 4;
    float4 v = *(const float4*)&x[i];
    float4 b = *(const float4*)&b_pre[i & (DM - 1)];
    ushort4 o;
    o.x = f2bf(v.x - b.x); o.y = f2bf(v.y - b.y);
    o.z = f2bf(v.z - b.z); o.w = f2bf(v.w - b.w);
    *(ushort4*)&A[i] = o;
}

// Convert W_enc -> bf16   [DH, DM]
__global__ __launch_bounds__(256) void conv_w(
    const float* __restrict__ W, ushort* __restrict__ B)
{
    int i = (blockIdx.x * 256 + threadIdx.x) * 4;
    float4 v = *(const float4*)&W[i];
    ushort4 o;
    o.x = f2bf(v.x); o.y = f2bf(v.y); o.z = f2bf(v.z); o.w = f2bf(v.w);
    *(ushort4*)&B[i] = o;
}

// ---------------------------------------------------------------------------
// 256x256 8-phase bf16 MFMA GEMM + fused candidate extraction.
// Candidates (o > CAND_T) aggregated in LDS per row (capacity 24 per
// 256-col slice), then ONE global atomicAdd per (row, block) reserves a
// contiguous range in cand[row][512] -> exact counts, packed contiguous.
// ---------------------------------------------------------------------------
#define LDS_A(par, ks)  ((par) * 65536 + (ks) * 16384)
#define LDS_B(par, ks)  ((par) * 65536 + 32768 + (ks) * 16384)

__global__ __launch_bounds__(512, 2) void gemm8ph(
    const ushort* __restrict__ A, const ushort* __restrict__ B,
    const float* __restrict__ b_act, float* __restrict__ pre,
    uint* __restrict__ cand, int* __restrict__ ccnt, uint* __restrict__ flags)
{
    __shared__ __align__(16) char smem[131072];

    const int tid  = threadIdx.x;
    const int wid  = tid >> 6;
    const int lane = tid & 63;
    const int wm   = wid >> 2;        // 0..1
    const int wn   = wid & 3;         // 0..3

    const int swz  = (blockIdx.x & 7) * 256 + (blockIdx.x >> 3);
    const int row0 = (swz & 31) * 256;
    const int col0 = (swz >> 5) * 256;

    f32x4 acc[8][4] = {};

    auto stage = [&](const ushort* __restrict__ g, int grow0, int gk0,
                     int region) {
        #pragma unroll
        for (int i = 0; i < 2; ++i) {
            int c    = i * 512 + wid * 64 + lane;
            int row  = c >> 2;
            int slot = (c & 3) ^ ((row >> 1) & 3);
            load_lds16(g + (size_t)(grow0 + row) * DM + gk0 + slot * 8,
                       smem + region + (i * 512 + wid * 64) * 16);
        }
    };
    auto ld_frag = [&](int region, int row) -> bf16x8 {
        int slot = (lane >> 4) ^ ((row >> 1) & 3);
        return *(const bf16x8*)(smem + region + row * 64 + slot * 16);
    };

    const int ar = wm * 128 + (lane & 15);
    const int br = wn * 64 + (lane & 15);

    // prologue: stage tile 0
    stage(A, row0, 0,  LDS_A(0, 0));
    stage(B, col0, 0,  LDS_B(0, 0));
    stage(A, row0, 32, LDS_A(0, 1));
    stage(B, col0, 32, LDS_B(0, 1));

    for (int t = 0; t < NT - 1; ++t) {
        const int par  = t & 1;
        const int npar = par ^ 1;
        const int k0n  = (t + 1) * 64;

        // ---- phase 0
        stage(A, row0, k0n, LDS_A(npar, 0));
        asm volatile("s_waitcnt vmcnt(6)" ::: "memory");
        __builtin_amdgcn_s_barrier();
        asm volatile("" ::: "memory");

        bf16x8 af[8];
        #pragma unroll
        for (int mf = 0; mf < 8; ++mf)
            af[mf] = ld_frag(LDS_A(par, 0), ar + mf * 16);
        {
            bf16x8 b0 = ld_frag(LDS_B(par, 0), br);
            bf16x8 b1 = ld_frag(LDS_B(par, 0), br + 16);
            __builtin_amdgcn_s_setprio(1);
            #pragma unroll
            for (int mf = 0; mf < 8; ++mf) {
                acc[mf][0] = __builtin_amdgcn_mfma_f32_16x16x32_bf16(af[mf], b0, acc[mf][0], 0, 0, 0);
                acc[mf][1] = __builtin_amdgcn_mfma_f32_16x16x32_bf16(af[mf], b1, acc[mf][1], 0, 0, 0);
            }
            __builtin_amdgcn_s_setprio(0);
        }
        // ---- phase 1
        stage(B, col0, k0n, LDS_B(npar, 0));
        {
            bf16x8 b2 = ld_frag(LDS_B(par, 0), br + 32);
            bf16x8 b3 = ld_frag(LDS_B(par, 0), br + 48);
            __builtin_amdgcn_s_setprio(1);
            #pragma unroll
            for (int mf = 0; mf < 8; ++mf) {
                acc[mf][2] = __builtin_amdgcn_mfma_f32_16x16x32_bf16(af[mf], b2, acc[mf][2], 0, 0, 0);
                acc[mf][3] = __builtin_amdgcn_mfma_f32_16x16x32_bf16(af[mf], b3, acc[mf][3], 0, 0, 0);
            }
            __builtin_amdgcn_s_setprio(0);
        }
        // ---- phase 2
        stage(A, row0, k0n + 32, LDS_A(npar, 1));
        asm volatile("s_waitcnt vmcnt(6)" ::: "memory");
        __builtin_amdgcn_s_barrier();
        asm volatile("" ::: "memory");

        #pragma unroll
        for (int mf = 0; mf < 8; ++mf)
            af[mf] = ld_frag(LDS_A(par, 1), ar + mf * 16);
        {
            bf16x8 b0 = ld_frag(LDS_B(par, 1), br);
            bf16x8 b1 = ld_frag(LDS_B(par, 1), br + 16);
            __builtin_amdgcn_s_setprio(1);
            #pragma unroll
            for (int mf = 0; mf < 8; ++mf) {
                acc[mf][0] = __builtin_amdgcn_mfma_f32_16x16x32_bf16(af[mf], b0, acc[mf][0], 0, 0, 0);
                acc[mf][1] = __builtin_amdgcn_mfma_f32_16x16x32_bf16(af[mf], b1, acc[mf][1], 0, 0, 0);
            }
            __builtin_amdgcn_s_setprio(0);
        }
        // ---- phase 3
        stage(B, col0, k0n + 32, LDS_B(npar, 1));
        {
            bf16x8 b2 = ld_frag(LDS_B(par, 1), br + 32);
            bf16x8 b3 = ld_frag(LDS_B(par, 1), br + 48);
            __builtin_amdgcn_s_setprio(1);
            #pragma unroll
            for (int mf = 0; mf < 8; ++mf) {
                acc[mf][2] = __builtin_amdgcn_mfma_f32_16x16x32_bf16(af[mf], b2, acc[mf][2], 0, 0, 0);
                acc[mf][3] = __builtin_amdgcn_mfma_f32_16x16x32_bf16(af[mf], b3, acc[mf][3], 0, 0, 0);
            }
            __builtin_amdgcn_s_setprio(0);
        }
    }

    // ---- peeled last tile (nothing staged; counted waits drain 4 -> 0)
    {
        const int par = (NT - 1) & 1;
        asm volatile("s_waitcnt vmcnt(4)" ::: "memory");
        __builtin_amdgcn_s_barrier();
        asm volatile("" ::: "memory");

        bf16x8 af[8];
        #pragma unroll
        for (int mf = 0; mf < 8; ++mf)
            af[mf] = ld_frag(LDS_A(par, 0), ar + mf * 16);
        {
            bf16x8 b0 = ld_frag(LDS_B(par, 0), br);
            bf16x8 b1 = ld_frag(LDS_B(par, 0), br + 16);
            bf16x8 b2 = ld_frag(LDS_B(par, 0), br + 32);
            bf16x8 b3 = ld_frag(LDS_B(par, 0), br + 48);
            __builtin_amdgcn_s_setprio(1);
            #pragma unroll
            for (int mf = 0; mf < 8; ++mf) {
                acc[mf][0] = __builtin_amdgcn_mfma_f32_16x16x32_bf16(af[mf], b0, acc[mf][0], 0, 0, 0);
                acc[mf][1] = __builtin_amdgcn_mfma_f32_16x16x32_bf16(af[mf], b1, acc[mf][1], 0, 0, 0);
                acc[mf][2] = __builtin_amdgcn_mfma_f32_16x16x32_bf16(af[mf], b2, acc[mf][2], 0, 0, 0);
                acc[mf][3] = __builtin_amdgcn_mfma_f32_16x16x32_bf16(af[mf], b3, acc[mf][3], 0, 0, 0);
            }
            __builtin_amdgcn_s_setprio(0);
        }
        asm volatile("s_waitcnt vmcnt(0)" ::: "memory");
        __builtin_amdgcn_s_barrier();
        asm volatile("" ::: "memory");

        #pragma unroll
        for (int mf = 0; mf < 8; ++mf)
            af[mf] = ld_frag(LDS_A(par, 1), ar + mf * 16);
        {
            bf16x8 b0 = ld_frag(LDS_B(par, 1), br);
            bf16x8 b1 = ld_frag(LDS_B(par, 1), br + 16);
            bf16x8 b2 = ld_frag(LDS_B(par, 1), br + 32);
            bf16x8 b3 = ld_frag(LDS_B(par, 1), br + 48);
            __builtin_amdgcn_s_setprio(1);
            #pragma unroll
            for (int mf = 0; mf < 8; ++mf) {
                acc[mf][0] = __builtin_amdgcn_mfma_f32_16x16x32_bf16(af[mf], b0, acc[mf][0], 0, 0, 0);
                acc[mf][1] = __builtin_amdgcn_mfma_f32_16x16x32_bf16(af[mf], b1, acc[mf][1], 0, 0, 0);
                acc[mf][2] = __builtin_amdgcn_mfma_f32_16x16x32_bf16(af[mf], b2, acc[mf][2], 0, 0, 0);
                acc[mf][3] = __builtin_amdgcn_mfma_f32_16x16x32_bf16(af[mf], b3, acc[mf][3], 0, 0, 0);
            }
            __builtin_amdgcn_s_setprio(0);
        }
    }

    // ---- epilogue: C-write + LDS-aggregated candidate extraction
    __syncthreads();                       // all waves done with LDS tiles
    uint* cnt = (uint*)smem;               // [256]
    uint* buf = (uint*)(smem + 1024);      // [256][CSLOT]
    if (tid < 256) cnt[tid] = 0;
    __syncthreads();

    float bav[4];
    #pragma unroll
    for (int nf = 0; nf < 4; ++nf)
        bav[nf] = b_act[col0 + wn * 64 + nf * 16 + (lane & 15)];

    #pragma unroll
    for (int mf = 0; mf < 8; ++mf) {
        const int lrow = wm * 128 + mf * 16 + (lane >> 4) * 4;
        const int gcol = col0 + wn * 64 + (lane & 15);
        #pragma unroll
        for (int r = 0; r < 4; ++r) {
            #pragma unroll
            for (int nf = 0; nf < 4; ++nf) {
                float o = acc[mf][nf][r] + bav[nf];
                pre[(size_t)(row0 + lrow + r) * DH + gcol + nf * 16] = o;
                if (o > CAND_T) {
                    uint pos = atomicAdd(&cnt[lrow + r], 1u);
                    if (pos < CSLOT)
                        buf[(lrow + r) * CSLOT + pos] =
                            ((uint)f2bf(o) << 16) | (uint)(16383 - (gcol + nf * 16));
                }
            }
        }
    }
    __syncthreads();
    if (tid < 256) {
        uint c = cnt[tid];
        if (c > 0) {
            uint m = c < CSLOT ? c : CSLOT;
            uint base = (uint)atomicAdd(&ccnt[row0 + tid], (int)m);
            if (c > CSLOT || base + c > NCAND) flags[row0 + tid] = 1u;
            for (uint k = 0; k < m && base + k < NCAND; ++k)
                cand[(size_t)(row0 + tid) * NCAND + base + k] = buf[tid * CSLOT + k];
        }
    }
}

// ---------------------------------------------------------------------------
// Fused top-32: read packed candidate range (exact count, contiguous),
// rank-by-count bounded to n, zone re-rank over zlist only; fallback to
// full-row bisection only on overflow (expected never). Zeroes sparse row.
// ---------------------------------------------------------------------------
__global__ __launch_bounds__(512) void topk_fused(
    const float* __restrict__ x, const float* __restrict__ b_pre,
    const float* __restrict__ W, const float* __restrict__ b_act,
    const uint* __restrict__ cand, const int* __restrict__ ccnt,
    const uint* __restrict__ flags, const float* __restrict__ pre,
    float* __restrict__ sparse, float* __restrict__ vals, int* __restrict__ inds)
{
    const int row = blockIdx.x;
    const int tid = threadIdx.x;
    const int wid = tid >> 6, lane = tid & 63;

    // zero sparse row (4096 float4 / 512 threads)
    float4 z4 = {0.f, 0.f, 0.f, 0.f};
    float4* srow = (float4*)(sparse + (size_t)row * DH);
    #pragma unroll
    for (int i = 0; i < 8; ++i) srow[tid + i * 512] = z4;

    __shared__ float xs[DM];
    for (int i = tid; i < DM; i += 512)
        xs[i] = x[(size_t)row * DM + i] - b_pre[i];

    __shared__ float sv[NCAND];
    __shared__ float sex[NCAND];
    __shared__ int   si[NCAND];
    __shared__ int   zlist[NCAND];
    __shared__ float sa32;
    __shared__ int   scin, zn, nl;

    int n = min(ccnt[row], NCAND);
    {
        uint pk = (tid < n) ? cand[(size_t)row * NCAND + tid] : 0u;
        sv[tid] = (tid < n) ? bf2f((ushort)(pk >> 16)) : -1e30f;
        si[tid] = (tid < n) ? (int)(16383u - (pk & 0x3FFFu)) : -1;
    }
    if (tid == 0) { scin = 0; zn = 0; sa32 = -1e30f; }
    if (tid < KTOP) {
        vals[(size_t)row * KTOP + tid] = 0.f;
        inds[(size_t)row * KTOP + tid] = -1;
    }
    __syncthreads();

    // fallback (expected ~never): overflow or degenerate
    const bool fb = (flags[row] != 0u) || n < 64;
    if (fb) {
        sv[tid] = -1e30f; si[tid] = -1;
        if (tid == 0) nl = 0;
        __syncthreads();
        const float* __restrict__ p = pre + (size_t)row * DH;
        float v[32];
        #pragma unroll
        for (int j = 0; j < 32; ++j) v[j] = p[j * 512 + tid];

        __shared__ int scount;
        float lo = -30.f, hi = 30.f, t = 0.f;
        for (int it = 0; it < 20; ++it) {
            t = 0.5f * (lo + hi);
            int c = 0;
            #pragma unroll
            for (int j = 0; j < 32; ++j) c += (v[j] > t);
            #pragma unroll
            for (int off = 32; off; off >>= 1) c += __shfl_down(c, off);
            if (tid == 0) scount = 0;
            __syncthreads();
            if ((tid & 63) == 0) atomicAdd(&scount, c);
            __syncthreads();
            int total = scount;
            __syncthreads();
            if (total >= 96 && total <= 450) break;
            if (total < 96) hi = t; else lo = t;
        }
        #pragma unroll
        for (int j = 0; j < 32; ++j) {
            if (v[j] > t) {
                int p2 = atomicAdd(&nl, 1);
                if (p2 < NCAND) { sv[p2] = v[j]; si[p2] = j * 512 + tid; }
            }
        }
        __syncthreads();
        n = min(nl, NCAND);
    }

    const float v  = sv[tid];
    const int   id = si[tid];
    sex[tid] = v;
    __syncthreads();

    // rank by count (val desc, idx asc), bounded to n (padded to 64)
    const int n_pad = (n + 63) & ~63;
    int rank = 0;
    for (int j = 0; j < n_pad; ++j) {
        float ov = sv[j];
        rank += (ov > v) || (ov == v && si[j] < id);
    }
    if (rank == 31) sa32 = v;
    __syncthreads();

    const float a32 = sa32;
    const bool cin  = v > a32 + DZ;
    const bool zone = !cin && (v >= a32 - DZ) && (id >= 0);

    unsigned long long bal = __ballot(cin);
    if (lane == 0) atomicAdd(&scin, (int)__popcll(bal));
    if (zone) { int p = atomicAdd(&zn, 1); zlist[p] = tid; }
    __syncthreads();

    const int cin_total = scin;
    const int znum = zn;

    // exact f32 recompute of zone members, one per wave (W rows L3-resident)
    for (int m = wid; m < znum; m += 8) {
        int t = zlist[m];
        int h = si[t];
        const float* wrow = W + (size_t)h * DM;
        float s = 0.f;
        #pragma unroll
        for (int c = 0; c < 16; ++c)
            s = fmaf(xs[lane + c * 64], wrow[lane + c * 64], s);
        #pragma unroll
        for (int off = 32; off; off >>= 1) s += __shfl_down(s, off);
        if (lane == 0) sex[t] = s + b_act[h];
    }
    __syncthreads();

    int slot = -1;
    float outv = 0.f;
    if (cin) { slot = rank; outv = v; }
    else if (zone) {
        float ev = sex[tid];
        int zrank = 0;
        for (int j = 0; j < znum; ++j) {
            int t2 = zlist[j];
            float ov = sex[t2];
            zrank += (ov > ev) || (ov == ev && si[t2] < id);
        }
        if (zrank < KTOP - cin_total) { slot = cin_total + zrank; outv = ev; }
    }
    if (slot >= 0 && slot < KTOP) {
        float r = fmaxf(outv, 0.f);
        vals[(size_t)row * KTOP + slot] = r;
        inds[(size_t)row * KTOP + slot] = id;
        sparse[(size_t)row * DH + id] = r;
    }
}

// ---------------------------------------------------------------------------
// Transpose W_dec [DM, DH] f32 -> W_dec^T [DH, DM] bf16
// ---------------------------------------------------------------------------
__global__ __launch_bounds__(256) void transpose_dec(
    const float* __restrict__ W, ushort* __restrict__ WT)
{
    __shared__ float t[32][33];
    const int tx = threadIdx.x;
    const int ty = threadIdx.y;
    const int h0 = blockIdx.x * 32;
    const int d0 = blockIdx.y * 32;
    #pragma unroll
    for (int r = 0; r < 4; ++r)
        t[ty + r * 8][tx] = W[(size_t)(d0 + ty + r * 8) * DH + h0 + tx];
    __syncthreads();
    #pragma unroll
    for (int r = 0; r < 4; ++r)
        WT[(size_t)(h0 + ty + r * 8) * DM + d0 + tx] = f2bf(t[tx][ty + r * 8]);
}

// ---------------------------------------------------------------------------
// Decode: recon[n][d] = sum_j vals[n][j] * WdecT[inds[n][j]][d] + b_pre[d]
// ---------------------------------------------------------------------------
__global__ __launch_bounds__(256) void recon_kernel(
    const float* __restrict__ vals, const int* __restrict__ inds,
    const ushort* __restrict__ wdecT, const float* __restrict__ b_pre,
    float* __restrict__ recon)
{
    const int row = blockIdx.x;
    const int tid = threadIdx.x;
    __shared__ float lval[KTOP];
    __shared__ int   lind[KTOP];
    if (tid < KTOP) {
        lval[tid] = vals[(size_t)row * KTOP + tid];
        lind[tid] = inds[(size_t)row * KTOP + tid];
    }
    __syncthreads();

    const int d = tid * 4;
    float4 a = *(const float4*)&b_pre[d];
    #pragma unroll 8
    for (int j = 0; j < KTOP; ++j) {
        float vj = lval[j];
        int h = lind[j];
        if (vj != 0.f && h >= 0) {
            ushort4 w = *(const ushort4*)&wdecT[(size_t)h * DM + d];
            a.x = fmaf(vj, bf2f(w.x), a.x);
            a.y = fmaf(vj, bf2f(w.y), a.y);
            a.z = fmaf(vj, bf2f(w.z), a.z);
            a.w = fmaf(vj, bf2f(w.w), a.w);
        }
    }
    *(float4*)&recon[(size_t)row * DM + d] = a;
}

// ---------------------------------------------------------------------------
extern "C" void kernel_launch(void* const* d_in, const int* in_sizes, int n_in,
                              void* d_out, int out_size, void* d_ws, size_t ws_size,
                              hipStream_t stream)
{
    const float* x     = (const float*)d_in[0];
    const float* W_enc = (const float*)d_in[1];
    const float* W_dec = (const float*)d_in[2];
    const float* b_pre = (const float*)d_in[3];
    const float* b_act = (const float*)d_in[4];

    float* recon  = (float*)d_out;                       // [N, DM]
    float* sparse = recon + (size_t)N_TOK * DM;          // [N, DH]
    float* pre    = sparse + (size_t)N_TOK * DH;         // [N, DH]

    // bf16 staging of A/B inside the sparse output region (zeroed later by
    // topk_fused, which runs after gemm has consumed them)
    ushort* Abf = (ushort*)sparse;                       // 16.8 MB
    ushort* Bbf = Abf + (size_t)N_TOK * DM;              // 33.5 MB

    // workspace (~52.4 MB, proven footprint)
    int*    ccnt  = (int*)d_ws;                                   // 32 KB
    uint*   flags = (uint*)(ccnt + N_TOK);                        // 32 KB
    float*  vals  = (float*)(flags + N_TOK);                      // 1.05 MB
    int*    inds  = (int*)(vals + (size_t)N_TOK * KTOP);          // 1.05 MB
    uint*   cand  = (uint*)(inds + (size_t)N_TOK * KTOP);         // 16.78 MB
    ushort* wdecT = (ushort*)(cand + (size_t)N_TOK * NCAND);      // 33.5 MB

    // zero counters + flags only (64 KB; stale cand beyond count never read)
    hipMemsetAsync(ccnt, 0, 2 * N_TOK * sizeof(int), stream);

    conv_x<<<N_TOK * DM / 1024, 256, 0, stream>>>(x, b_pre, Abf);
    conv_w<<<DH * DM / 1024, 256, 0, stream>>>(W_enc, Bbf);

    gemm8ph<<<(N_TOK / 256) * (DH / 256), 512, 0, stream>>>(
        Abf, Bbf, b_act, pre, cand, ccnt, flags);

    transpose_dec<<<dim3(DH / 32, DM / 32), dim3(32, 8), 0, stream>>>(W_dec, wdecT);

    topk_fused<<<N_TOK, 512, 0, stream>>>(x, b_pre, W_enc, b_act,
                                          cand, ccnt, flags, pre,
                                          sparse, vals, inds);

    recon_kernel<<<N_TOK, 256, 0, stream>>>(vals, inds, wdecT, b_pre, recon);
}

// Round 9
// 783.211 us; speedup vs baseline: 1.5362x; 1.0210x over previous
//
#include <hip/hip_runtime.h>
#include <hip/hip_bf16.h>

#define N_TOK   8192
#define DM      1024     // d_model
#define DH      16384    // d_hidden
#define KTOP    32
#define NCAND   512      // candidate capacity per row (atomic-range packed)
#define CSLOT   16       // LDS slots per (row, 128-col slice); Poisson(~1.8)
#define CAND_T  2.2f     // fixed threshold (validated end-to-end rounds 3/6/7)
#define DZ      0.08f    // zone half-width >= gemm err (0.031) + bf16 quant (0.008)

typedef unsigned int uint;
typedef __attribute__((ext_vector_type(8))) short bf16x8;
typedef __attribute__((ext_vector_type(4))) float f32x4;
typedef __attribute__((ext_vector_type(2))) float f32x2;

__device__ inline ushort f2bf(float f) {
    uint u = __float_as_uint(f);
    uint r = (u + 0x7FFFu + ((u >> 16) & 1u)) >> 16;
    return (ushort)r;
}
__device__ inline float bf2f(ushort u) {
    return __uint_as_float(((uint)u) << 16);
}

__device__ inline void load_lds16(const void* g, void* l) {
    __builtin_amdgcn_global_load_lds(
        (const __attribute__((address_space(1))) void*)g,
        (__attribute__((address_space(3))) void*)l, 16, 0, 0);
}

// ---------------------------------------------------------------------------
// Fused conversion: A = bf16(x - b_pre) [N_TOK,DM]; B = bf16(W_enc) [DH,DM]
// Block-uniform branch (A region is exactly 8192 blocks).
// ---------------------------------------------------------------------------
#define NA (N_TOK * DM)
__global__ __launch_bounds__(256) void conv_fused(
    const float* __restrict__ x, const float* __restrict__ b_pre,
    const float* __restrict__ W, ushort* __restrict__ A, ushort* __restrict__ B)
{
    int i = (blockIdx.x * 256 + threadIdx.x) * 4;
    if (i < NA) {
        float4 v = *(const float4*)&x[i];
        float4 b = *(const float4*)&b_pre[i & (DM - 1)];
        ushort4 o;
        o.x = f2bf(v.x - b.x); o.y = f2bf(v.y - b.y);
        o.z = f2bf(v.z - b.z); o.w = f2bf(v.w - b.w);
        *(ushort4*)&A[i] = o;
    } else {
        int j = i - NA;
        float4 v = *(const float4*)&W[j];
        ushort4 o;
        o.x = f2bf(v.x); o.y = f2bf(v.y); o.z = f2bf(v.z); o.w = f2bf(v.w);
        *(ushort4*)&B[j] = o;
    }
}

// ---------------------------------------------------------------------------
// bf16 MFMA GEMM (proven m97 128x128 structure, 3 blocks/CU) + fused
// candidate extraction (LDS-aggregated, exact-count atomic-range packing)
// + nontemporal pre stores.
// ---------------------------------------------------------------------------
__global__ __launch_bounds__(256, 3) void gemm_bf16(
    const ushort* __restrict__ A, const ushort* __restrict__ B,
    const float* __restrict__ b_act, float* __restrict__ pre,
    uint* __restrict__ cand, int* __restrict__ ccnt, uint* __restrict__ flags)
{
    __shared__ ushort As[128 * 64];   // 16 KB
    __shared__ ushort Bs[128 * 64];   // 16 KB

    const int tid  = threadIdx.x;
    const int wid  = tid >> 6;
    const int lane = tid & 63;
    const int wr   = wid >> 1;        // wave row 0..1
    const int wc   = wid & 1;         // wave col 0..1

    // XCD-aware bijective swizzle (8192 % 8 == 0), bn-major for L2 B reuse
    int swz = (blockIdx.x & 7) * 1024 + (blockIdx.x >> 3);
    const int bm = swz & 63;          // 64 row tiles
    const int bn = swz >> 6;          // 128 col tiles
    const int row0 = bm * 128;
    const int col0 = bn * 128;

    f32x4 acc[4][4] = {};

    const int chunk = wid * 64 + lane;
    for (int k0 = 0; k0 < DM; k0 += 64) {
        #pragma unroll
        for (int i = 0; i < 4; ++i) {
            int ch = i * 256 + chunk;
            int r  = ch >> 3;
            int c8 = (ch & 7) * 8;
            load_lds16(&A[(size_t)(row0 + r) * DM + k0 + c8],
                       &As[(size_t)(i * 256 + wid * 64) * 8]);
            load_lds16(&B[(size_t)(col0 + r) * DM + k0 + c8],
                       &Bs[(size_t)(i * 256 + wid * 64) * 8]);
        }
        __syncthreads();
        #pragma unroll
        for (int ks = 0; ks < 2; ++ks) {
            const int kb = ks * 32 + (lane >> 4) * 8;
            bf16x8 af[4], bfr[4];
            #pragma unroll
            for (int m = 0; m < 4; ++m)
                af[m] = *(const bf16x8*)&As[(wr * 64 + m * 16 + (lane & 15)) * 64 + kb];
            #pragma unroll
            for (int n = 0; n < 4; ++n)
                bfr[n] = *(const bf16x8*)&Bs[(wc * 64 + n * 16 + (lane & 15)) * 64 + kb];
            #pragma unroll
            for (int m = 0; m < 4; ++m)
                #pragma unroll
                for (int n = 0; n < 4; ++n)
                    acc[m][n] = __builtin_amdgcn_mfma_f32_16x16x32_bf16(
                        af[m], bfr[n], acc[m][n], 0, 0, 0);
        }
        __syncthreads();
    }

    // ---- epilogue: C-write (nontemporal) + LDS candidate aggregation
    uint* cnt = (uint*)As;             // [128]
    uint* buf = (uint*)As + 128;       // [128][CSLOT]  (8.7 KB, aliases As)
    if (tid < 128) cnt[tid] = 0;
    __syncthreads();

    const int ccol = col0 + wc * 64 + (lane & 15);
    float ba[4];
    #pragma unroll
    for (int n = 0; n < 4; ++n) ba[n] = b_act[ccol + n * 16];
    #pragma unroll
    for (int m = 0; m < 4; ++m) {
        const int lrow = wr * 64 + m * 16 + (lane >> 4) * 4;
        #pragma unroll
        for (int r = 0; r < 4; ++r) {
            #pragma unroll
            for (int n = 0; n < 4; ++n) {
                float o = acc[m][n][r] + ba[n];
                __builtin_nontemporal_store(
                    o, &pre[(size_t)(row0 + lrow + r) * DH + ccol + n * 16]);
                if (o > CAND_T) {
                    uint pos = atomicAdd(&cnt[lrow + r], 1u);
                    if (pos < CSLOT)
                        buf[(lrow + r) * CSLOT + pos] =
                            ((uint)f2bf(o) << 16) | (uint)(16383 - (ccol + n * 16));
                }
            }
        }
    }
    __syncthreads();
    if (tid < 128) {
        uint c = cnt[tid];
        if (c > 0) {
            uint m = c < CSLOT ? c : CSLOT;
            uint base = (uint)atomicAdd(&ccnt[row0 + tid], (int)m);
            if (c > CSLOT || base + c > NCAND) flags[row0 + tid] = 1u;
            for (uint k = 0; k < m && base + k < NCAND; ++k)
                cand[(size_t)(row0 + tid) * NCAND + base + k] = buf[tid * CSLOT + k];
        }
    }
}

// ---------------------------------------------------------------------------
// Fused top-32 + decode: candidate read -> rank -> zone exact repair ->
// scatter sparse + LDS winners -> recon row. Zeroes sparse row (nt stores).
// ---------------------------------------------------------------------------
__global__ __launch_bounds__(512) void topk_recon(
    const float* __restrict__ x, const float* __restrict__ b_pre,
    const float* __restrict__ W, const float* __restrict__ b_act,
    const uint* __restrict__ cand, const int* __restrict__ ccnt,
    const uint* __restrict__ flags, const float* __restrict__ pre,
    const ushort* __restrict__ wdecT,
    float* __restrict__ sparse, float* __restrict__ recon)
{
    const int row = blockIdx.x;
    const int tid = threadIdx.x;
    const int wid = tid >> 6, lane = tid & 63;

    // zero sparse row (4096 x 16B / 512 threads, nontemporal)
    f32x4 z4 = {0.f, 0.f, 0.f, 0.f};
    f32x4* srow = (f32x4*)(sparse + (size_t)row * DH);
    #pragma unroll
    for (int i = 0; i < 8; ++i)
        __builtin_nontemporal_store(z4, &srow[tid + i * 512]);

    __shared__ float xs[DM];
    for (int i = tid; i < DM; i += 512)
        xs[i] = x[(size_t)row * DM + i] - b_pre[i];

    __shared__ float sv[NCAND];
    __shared__ float sex[NCAND];
    __shared__ int   si[NCAND];
    __shared__ int   zlist[NCAND];
    __shared__ float svals[KTOP];
    __shared__ int   sinds[KTOP];
    __shared__ float sa32;
    __shared__ int   scin, zn, nl;

    int n = min(ccnt[row], NCAND);
    {
        uint pk = (tid < n) ? cand[(size_t)row * NCAND + tid] : 0u;
        sv[tid] = (tid < n) ? bf2f((ushort)(pk >> 16)) : -1e30f;
        si[tid] = (tid < n) ? (int)(16383u - (pk & 0x3FFFu)) : -1;
    }
    if (tid == 0) { scin = 0; zn = 0; sa32 = -1e30f; }
    if (tid < KTOP) { svals[tid] = 0.f; sinds[tid] = -1; }
    __syncthreads();

    // fallback (expected ~never): overflow or degenerate
    const bool fb = (flags[row] != 0u) || n < 64;
    if (fb) {
        sv[tid] = -1e30f; si[tid] = -1;
        if (tid == 0) nl = 0;
        __syncthreads();
        const float* __restrict__ p = pre + (size_t)row * DH;
        float v[32];
        #pragma unroll
        for (int j = 0; j < 32; ++j) v[j] = p[j * 512 + tid];

        __shared__ int scount;
        float lo = -30.f, hi = 30.f, t = 0.f;
        for (int it = 0; it < 20; ++it) {
            t = 0.5f * (lo + hi);
            int c = 0;
            #pragma unroll
            for (int j = 0; j < 32; ++j) c += (v[j] > t);
            #pragma unroll
            for (int off = 32; off; off >>= 1) c += __shfl_down(c, off);
            if (tid == 0) scount = 0;
            __syncthreads();
            if ((tid & 63) == 0) atomicAdd(&scount, c);
            __syncthreads();
            int total = scount;
            __syncthreads();
            if (total >= 96 && total <= 450) break;
            if (total < 96) hi = t; else lo = t;
        }
        #pragma unroll
        for (int j = 0; j < 32; ++j) {
            if (v[j] > t) {
                int p2 = atomicAdd(&nl, 1);
                if (p2 < NCAND) { sv[p2] = v[j]; si[p2] = j * 512 + tid; }
            }
        }
        __syncthreads();
        n = min(nl, NCAND);
    }

    const float v  = sv[tid];
    const int   id = si[tid];
    sex[tid] = v;
    __syncthreads();

    // rank by count (val desc, idx asc), bounded to n (padded to 64)
    const int n_pad = (n + 63) & ~63;
    int rank = 0;
    for (int j = 0; j < n_pad; ++j) {
        float ov = sv[j];
        rank += (ov > v) || (ov == v && si[j] < id);
    }
    if (rank == 31) sa32 = v;
    __syncthreads();

    const float a32 = sa32;
    const bool cin  = v > a32 + DZ;
    const bool zone = !cin && (v >= a32 - DZ) && (id >= 0);

    unsigned long long bal = __ballot(cin);
    if (lane == 0) atomicAdd(&scin, (int)__popcll(bal));
    if (zone) { int p = atomicAdd(&zn, 1); zlist[p] = tid; }
    __syncthreads();

    const int cin_total = scin;
    const int znum = zn;

    // exact f32 recompute of zone members, one per wave (W rows L3-resident)
    for (int m = wid; m < znum; m += 8) {
        int t = zlist[m];
        int h = si[t];
        const float* wrow = W + (size_t)h * DM;
        float s = 0.f;
        #pragma unroll
        for (int c = 0; c < 16; ++c)
            s = fmaf(xs[lane + c * 64], wrow[lane + c * 64], s);
        #pragma unroll
        for (int off = 32; off; off >>= 1) s += __shfl_down(s, off);
        if (lane == 0) sex[t] = s + b_act[h];
    }
    __syncthreads();

    int slot = -1;
    float outv = 0.f;
    if (cin) { slot = rank; outv = v; }
    else if (zone) {
        float ev = sex[tid];
        int zrank = 0;
        for (int j = 0; j < znum; ++j) {
            int t2 = zlist[j];
            float ov = sex[t2];
            zrank += (ov > ev) || (ov == ev && si[t2] < id);
        }
        if (zrank < KTOP - cin_total) { slot = cin_total + zrank; outv = ev; }
    }
    if (slot >= 0 && slot < KTOP) {
        float r = fmaxf(outv, 0.f);
        svals[slot] = r;
        sinds[slot] = id;
        sparse[(size_t)row * DH + id] = r;
    }
    __syncthreads();

    // ---- fused decode: recon[row][d] = sum_j svals[j]*wdecT[sinds[j]][d]+b_pre[d]
    const int d0 = tid * 2;
    f32x2 a;
    a.x = b_pre[d0]; a.y = b_pre[d0 + 1];
    #pragma unroll 8
    for (int j = 0; j < KTOP; ++j) {
        float vj = svals[j];
        int h = sinds[j];
        if (vj != 0.f && h >= 0) {
            ushort2 w = *(const ushort2*)&wdecT[(size_t)h * DM + d0];
            a.x = fmaf(vj, bf2f(w.x), a.x);
            a.y = fmaf(vj, bf2f(w.y), a.y);
        }
    }
    __builtin_nontemporal_store(a, (f32x2*)&recon[(size_t)row * DM + d0]);
}

// ---------------------------------------------------------------------------
// Transpose W_dec [DM, DH] f32 -> W_dec^T [DH, DM] bf16
// ---------------------------------------------------------------------------
__global__ __launch_bounds__(256) void transpose_dec(
    const float* __restrict__ W, ushort* __restrict__ WT)
{
    __shared__ float t[32][33];
    const int tx = threadIdx.x;
    const int ty = threadIdx.y;
    const int h0 = blockIdx.x * 32;
    const int d0 = blockIdx.y * 32;
    #pragma unroll
    for (int r = 0; r < 4; ++r)
        t[ty + r * 8][tx] = W[(size_t)(d0 + ty + r * 8) * DH + h0 + tx];
    __syncthreads();
    #pragma unroll
    for (int r = 0; r < 4; ++r)
        WT[(size_t)(h0 + ty + r * 8) * DM + d0 + tx] = f2bf(t[tx][ty + r * 8]);
}

// ---------------------------------------------------------------------------
extern "C" void kernel_launch(void* const* d_in, const int* in_sizes, int n_in,
                              void* d_out, int out_size, void* d_ws, size_t ws_size,
                              hipStream_t stream)
{
    const float* x     = (const float*)d_in[0];
    const float* W_enc = (const float*)d_in[1];
    const float* W_dec = (const float*)d_in[2];
    const float* b_pre = (const float*)d_in[3];
    const float* b_act = (const float*)d_in[4];

    float* recon  = (float*)d_out;                       // [N, DM]
    float* sparse = recon + (size_t)N_TOK * DM;          // [N, DH]
    float* pre    = sparse + (size_t)N_TOK * DH;         // [N, DH]

    // bf16 staging of A/B inside the sparse output region (zeroed later by
    // topk_recon, which runs after gemm has consumed them)
    ushort* Abf = (ushort*)sparse;                       // 16.8 MB
    ushort* Bbf = Abf + (size_t)N_TOK * DM;              // 33.5 MB

    // workspace (~50.4 MB, under proven 52.4 MB footprint)
    int*    ccnt  = (int*)d_ws;                                   // 32 KB
    uint*   flags = (uint*)(ccnt + N_TOK);                        // 32 KB
    uint*   cand  = (uint*)(flags + N_TOK);                       // 16.78 MB
    ushort* wdecT = (ushort*)(cand + (size_t)N_TOK * NCAND);      // 33.5 MB

    // zero counters + flags only (64 KB; stale cand beyond count never read)
    (void)hipMemsetAsync(ccnt, 0, 2 * N_TOK * sizeof(int), stream);

    conv_fused<<<(NA + DH * DM) / 1024, 256, 0, stream>>>(x, b_pre, W_enc, Abf, Bbf);

    gemm_bf16<<<(N_TOK / 128) * (DH / 128), 256, 0, stream>>>(
        Abf, Bbf, b_act, pre, cand, ccnt, flags);

    transpose_dec<<<dim3(DH / 32, DM / 32), dim3(32, 8), 0, stream>>>(W_dec, wdecT);

    topk_recon<<<N_TOK, 512, 0, stream>>>(x, b_pre, W_enc, b_act,
                                          cand, ccnt, flags, pre, wdecT,
                                          sparse, recon);
}